// Round 7
// baseline (150.492 us; speedup 1.0000x reference)
//
#include <hip/hip_runtime.h>
#include <math.h>

#define HH 1024
#define WW 1024
#define PADK 15
#define RB 16
#define TPB 512
#define EPSV 1e-5f
#define INV_K2 (1.0f / 961.0f)

__device__ __forceinline__ float4 ld4(const float* p) {
    return *reinterpret_cast<const float4*>(p);
}

// Horizontal 31-window sums for 8 consecutive cols owned by lane l.
// sw = wave's LDS array (16 halo | 512 owned | 16 halo). Lane l owns words
// 16+8l..16+8l+7; window for owned col q needs words 8l+(q+1 .. q+31).
// Reads 10 aligned float4 (words 8l..8l+39), streams the 28-elem base,
// then 7 incremental steps: win(q+1) = win(q) + enter - leave.
__device__ __forceinline__ void hwin31(const float* __restrict__ sw, int l,
                                       float wins[8]) {
    const float* p = sw + 8 * l;
    float4 R0 = ld4(p);            // wv[0..3]
    float4 R1 = ld4(p + 4);        // wv[4..7]
    float4 v2 = ld4(p + 8);
    float4 v3 = ld4(p + 12);
    float4 v4 = ld4(p + 16);
    float4 v5 = ld4(p + 20);
    float4 v6 = ld4(p + 24);
    float4 v7 = ld4(p + 28);       // ..wv[31]
    float4 R8 = ld4(p + 32);       // wv[32..35]
    float4 R9 = ld4(p + 36);       // wv[36..39]

    float a0 = R1.x, a1 = R1.y, a2 = R1.z, a3 = R1.w;
    a0 += v2.x; a1 += v2.y; a2 += v2.z; a3 += v2.w;
    a0 += v3.x; a1 += v3.y; a2 += v3.z; a3 += v3.w;
    a0 += v4.x; a1 += v4.y; a2 += v4.z; a3 += v4.w;
    a0 += v5.x; a1 += v5.y; a2 += v5.z; a3 += v5.w;
    a0 += v6.x; a1 += v6.y; a2 += v6.z; a3 += v6.w;
    a0 += v7.x; a1 += v7.y; a2 += v7.z; a3 += v7.w;
    float base = (a0 + a1) + (a2 + a3);               // wv[4..31]

    wins[0] = base + ((R0.y + R0.z) + R0.w);          // + wv[1..3]
    wins[1] = wins[0] + (R8.x - R0.y);
    wins[2] = wins[1] + (R8.y - R0.z);
    wins[3] = wins[2] + (R8.z - R0.w);
    wins[4] = wins[3] + (R8.w - R1.x);
    wins[5] = wins[4] + (R9.x - R1.y);
    wins[6] = wins[5] + (R9.y - R1.z);
    wins[7] = wins[6] + (R9.z - R1.w);
}

__global__ __launch_bounds__(TPB) void lcn_kernel(const float* __restrict__ x,
                                                  float* __restrict__ out) {
    // 8 waves/block = 2 col-halves x 4 row-bands of 16 rows. Wave owns a
    // 512-col stripe, 8 cols/lane. Block covers a 64-row x 1024-col slab
    // (94 distinct rows fetched per 64 output -> 1.47x read amp, bands share
    // halo rows via L2). Per-wave private LDS vertical-sum arrays with
    // 16-col halos (544 + 8 pad). No __syncthreads: all LDS traffic is
    // wave-local; DS ops are in-order within a wave.
    __shared__ __align__(16) float sxl[8][552];
    __shared__ __align__(16) float sql[8][552];

    const int blk  = blockIdx.x;
    const int b    = blk >> 4;          // image
    const int seg  = blk & 15;          // 64-row slab within image
    const int t    = threadIdx.x;
    const int w    = t >> 6;            // wave 0..7
    const int l    = t & 63;            // lane
    const int half = w & 1;             // column half
    const int band = w >> 1;            // row band 0..3
    const int r0   = seg * 64 + band * RB;
    const int wc0  = half * 512;
    const int c0   = wc0 + l * 8;       // lane owns cols c0..c0+7

    float* __restrict__ sxw = sxl[w];
    float* __restrict__ sqw = sql[w];

    // halo: lanes 0-3 left halo float4s (cols wc0-16..wc0-1),
    //       lanes 4-7 right halo float4s (cols wc0+512..wc0+527)
    int hcol = 0;
    const bool hlane = (l < 8);
    if (l < 4)      hcol = wc0 - 16 + 4 * l;
    else if (l < 8) hcol = wc0 + 512 + 4 * (l - 4);
    const bool hvalid = hlane && (hcol >= 0) && (hcol < WW);
    const int  hidx   = (l < 4) ? 4 * l : 528 + 4 * (l - 4);

    const float* __restrict__ img  = x   + (size_t)b * HH * WW;
    float* __restrict__       oimg = out + (size_t)b * HH * WW;

    float4 sa = make_float4(0.f, 0.f, 0.f, 0.f);   // vertical sums, cols c0..c0+3
    float4 sb = make_float4(0.f, 0.f, 0.f, 0.f);   // cols c0+4..c0+7
    float4 qa = make_float4(0.f, 0.f, 0.f, 0.f);   // vertical sq-sums
    float4 qb = make_float4(0.f, 0.f, 0.f, 0.f);
    float4 hs  = make_float4(0.f, 0.f, 0.f, 0.f);  // halo sums
    float4 hs2 = make_float4(0.f, 0.f, 0.f, 0.f);

    // --- init vertical sliding sums for output row r0 ---
    {
        int lo = r0 - PADK; if (lo < 0) lo = 0;
        int hi = r0 + PADK; if (hi > HH - 1) hi = HH - 1;
        for (int r = lo; r <= hi; ++r) {
            const float* rowp = img + (size_t)r * WW;
            float4 va = ld4(rowp + c0);
            float4 vb = ld4(rowp + c0 + 4);
            sa.x += va.x;       sa.y += va.y;       sa.z += va.z;       sa.w += va.w;
            sb.x += vb.x;       sb.y += vb.y;       sb.z += vb.z;       sb.w += vb.w;
            qa.x += va.x*va.x;  qa.y += va.y*va.y;  qa.z += va.z*va.z;  qa.w += va.w*va.w;
            qb.x += vb.x*vb.x;  qb.y += vb.y*vb.y;  qb.z += vb.z*vb.z;  qb.w += vb.w*vb.w;
            if (hvalid) {
                float4 hv = ld4(rowp + hcol);
                hs.x  += hv.x;       hs.y  += hv.y;       hs.z  += hv.z;       hs.w  += hv.w;
                hs2.x += hv.x*hv.x;  hs2.y += hv.y*hv.y;  hs2.z += hv.z*hv.z;  hs2.w += hv.w*hv.w;
            }
        }
    }

    for (int i = 0; i < RB; ++i) {
        const int orow = r0 + i;
        if (i > 0) {
            const int radd = orow + PADK;
            const int rsub = orow - PADK - 1;
            if (radd < HH) {
                const float* rowp = img + (size_t)radd * WW;
                float4 va = ld4(rowp + c0);
                float4 vb = ld4(rowp + c0 + 4);
                sa.x += va.x;       sa.y += va.y;       sa.z += va.z;       sa.w += va.w;
                sb.x += vb.x;       sb.y += vb.y;       sb.z += vb.z;       sb.w += vb.w;
                qa.x += va.x*va.x;  qa.y += va.y*va.y;  qa.z += va.z*va.z;  qa.w += va.w*va.w;
                qb.x += vb.x*vb.x;  qb.y += vb.y*vb.y;  qb.z += vb.z*vb.z;  qb.w += vb.w*vb.w;
                if (hvalid) {
                    float4 hv = ld4(rowp + hcol);
                    hs.x  += hv.x;       hs.y  += hv.y;       hs.z  += hv.z;       hs.w  += hv.w;
                    hs2.x += hv.x*hv.x;  hs2.y += hv.y*hv.y;  hs2.z += hv.z*hv.z;  hs2.w += hv.w*hv.w;
                }
            }
            if (rsub >= 0) {
                const float* rowp = img + (size_t)rsub * WW;
                float4 va = ld4(rowp + c0);
                float4 vb = ld4(rowp + c0 + 4);
                sa.x -= va.x;       sa.y -= va.y;       sa.z -= va.z;       sa.w -= va.w;
                sb.x -= vb.x;       sb.y -= vb.y;       sb.z -= vb.z;       sb.w -= vb.w;
                qa.x -= va.x*va.x;  qa.y -= va.y*va.y;  qa.z -= va.z*va.z;  qa.w -= va.w*va.w;
                qb.x -= vb.x*vb.x;  qb.y -= vb.y*vb.y;  qb.z -= vb.z*vb.z;  qb.w -= vb.w*vb.w;
                if (hvalid) {
                    float4 hv = ld4(rowp + hcol);
                    hs.x  -= hv.x;       hs.y  -= hv.y;       hs.z  -= hv.z;       hs.w  -= hv.w;
                    hs2.x -= hv.x*hv.x;  hs2.y -= hv.y*hv.y;  hs2.z -= hv.z*hv.z;  hs2.w -= hv.w*hv.w;
                }
            }
        }

        // write this wave's vertical sums (owned + halo) to its LDS region
        *reinterpret_cast<float4*>(sxw + 16 + 8 * l)     = sa;
        *reinterpret_cast<float4*>(sxw + 16 + 8 * l + 4) = sb;
        *reinterpret_cast<float4*>(sqw + 16 + 8 * l)     = qa;
        *reinterpret_cast<float4*>(sqw + 16 + 8 * l + 4) = qb;
        if (hlane) {
            *reinterpret_cast<float4*>(sxw + hidx) = hs;    // zeros when !hvalid
            *reinterpret_cast<float4*>(sqw + hidx) = hs2;
        }
        // no barrier: DS ops are in-order within a wave

        // --- horizontal 31-window sums for the 8 owned cols ---
        float winx[8], winq[8];
        hwin31(sxw, l, winx);
        hwin31(sqw, l, winq);

        const float4 xc0 = ld4(img + (size_t)orow * WW + c0);
        const float4 xc1 = ld4(img + (size_t)orow * WW + c0 + 4);
        const float xcv[8] = {xc0.x, xc0.y, xc0.z, xc0.w,
                              xc1.x, xc1.y, xc1.z, xc1.w};
        float res[8];
        #pragma unroll
        for (int q = 0; q < 8; ++q) {
            float mean = winx[q] * INV_K2;
            float sq   = winq[q] * INV_K2;
            float sd   = sqrtf(fmaxf(sq - mean * mean, EPSV));
            float nrm  = (xcv[q] - mean) * __builtin_amdgcn_rcpf(sd + EPSV);
            float e    = __expf(-0.5f * nrm);
            res[q] = xcv[q] * 0.2f + 0.8f * __builtin_amdgcn_rcpf(1.0f + e);
        }
        float4 o0 = make_float4(res[0], res[1], res[2], res[3]);
        float4 o1 = make_float4(res[4], res[5], res[6], res[7]);
        *reinterpret_cast<float4*>(oimg + (size_t)orow * WW + c0)     = o0;
        *reinterpret_cast<float4*>(oimg + (size_t)orow * WW + c0 + 4) = o1;
    }
}

extern "C" void kernel_launch(void* const* d_in, const int* in_sizes, int n_in,
                              void* d_out, int out_size, void* d_ws, size_t ws_size,
                              hipStream_t stream) {
    const float* xin = (const float*)d_in[0];
    float* out = (float*)d_out;
    const int B = in_sizes[0] / (HH * WW);   // 32
    dim3 grid(B * 16);                       // 512 blocks x 8 waves
    dim3 block(TPB);
    hipLaunchKernelGGL(lcn_kernel, grid, block, 0, stream, xin, out);
}

// Round 8
// 138.213 us; speedup vs baseline: 1.0888x; 1.0888x over previous
//
#include <hip/hip_runtime.h>
#include <math.h>

#define HH 1024
#define WW 1024
#define PADK 15
#define RB 8
#define TPB 512
#define EPSV 1e-5f
#define INV_K2 (1.0f / 961.0f)

__device__ __forceinline__ float4 ld4(const float* p) {
    return *reinterpret_cast<const float4*>(p);
}

// XOR bank swizzle on LDS word index: b2 ^= b5. Keeps every 4-aligned
// float4 contiguous and 16B-aligned; spreads lane-stride-8-word access
// patterns (8 cols/lane) across all 32 banks (verified per-base by hand:
// write bases 16+8l / 20+8l and read bases 8l+4m all hit 8 distinct
// bank-quads per 8-lane group).
__device__ __forceinline__ int swz4(int w) {
    return w ^ (((w >> 5) & 1) << 2);
}

// Horizontal 31-window sums for the 8 consecutive cols owned by a lane.
// sw = wave's swizzled LDS array (16 halo | 512 owned | 16 halo, logical
// words 0..543). bw = 8*lane: window for owned col q needs logical words
// bw + (q+1 .. q+31). Reads 10 swizzled float4 (words bw..bw+39), streams
// the 28-elem base, then 7 incremental steps (r7-verified arithmetic).
__device__ __forceinline__ void hwin31(const float* __restrict__ sw, int bw,
                                       float wins[8]) {
    float4 R0 = ld4(sw + swz4(bw));        // wv[0..3]
    float4 R1 = ld4(sw + swz4(bw + 4));    // wv[4..7]
    float4 v2 = ld4(sw + swz4(bw + 8));
    float4 v3 = ld4(sw + swz4(bw + 12));
    float4 v4 = ld4(sw + swz4(bw + 16));
    float4 v5 = ld4(sw + swz4(bw + 20));
    float4 v6 = ld4(sw + swz4(bw + 24));
    float4 v7 = ld4(sw + swz4(bw + 28));   // ..wv[31]
    float4 R8 = ld4(sw + swz4(bw + 32));   // wv[32..35]
    float4 R9 = ld4(sw + swz4(bw + 36));   // wv[36..39]

    float a0 = R1.x, a1 = R1.y, a2 = R1.z, a3 = R1.w;
    a0 += v2.x; a1 += v2.y; a2 += v2.z; a3 += v2.w;
    a0 += v3.x; a1 += v3.y; a2 += v3.z; a3 += v3.w;
    a0 += v4.x; a1 += v4.y; a2 += v4.z; a3 += v4.w;
    a0 += v5.x; a1 += v5.y; a2 += v5.z; a3 += v5.w;
    a0 += v6.x; a1 += v6.y; a2 += v6.z; a3 += v6.w;
    a0 += v7.x; a1 += v7.y; a2 += v7.z; a3 += v7.w;
    float base = (a0 + a1) + (a2 + a3);               // wv[4..31]

    wins[0] = base + ((R0.y + R0.z) + R0.w);          // + wv[1..3]
    wins[1] = wins[0] + (R8.x - R0.y);
    wins[2] = wins[1] + (R8.y - R0.z);
    wins[3] = wins[2] + (R8.z - R0.w);
    wins[4] = wins[3] + (R8.w - R1.x);
    wins[5] = wins[4] + (R9.x - R1.y);
    wins[6] = wins[5] + (R9.y - R1.z);
    wins[7] = wins[6] + (R9.z - R1.w);
}

__global__ __launch_bounds__(TPB) void lcn_kernel(const float* __restrict__ x,
                                                  float* __restrict__ out) {
    // 8 waves/block = 2 col-halves x 4 row-bands of 8 rows (32-row slab).
    // Wave owns a 512-col stripe, 8 cols/lane. Grid = 1024 blocks ->
    // 4 blocks/CU x 8 waves = 32 waves/CU. Per-wave private swizzled LDS
    // vertical-sum arrays. No __syncthreads: all LDS traffic is wave-local;
    // DS ops are in-order within a wave.
    __shared__ __align__(16) float sxl[8][552];
    __shared__ __align__(16) float sql[8][552];

    const int blk  = blockIdx.x;
    const int b    = blk >> 5;          // image
    const int seg  = blk & 31;          // 32-row slab within image
    const int t    = threadIdx.x;
    const int w    = t >> 6;            // wave 0..7
    const int l    = t & 63;            // lane
    const int half = w & 1;             // column half
    const int band = w >> 1;            // row band 0..3
    const int r0   = seg * 32 + band * RB;
    const int wc0  = half * 512;
    const int c0   = wc0 + l * 8;       // lane owns cols c0..c0+7
    const int bw   = 8 * l;             // window read base (logical word)

    float* __restrict__ sxw = sxl[w];
    float* __restrict__ sqw = sql[w];

    // halo: lanes 0-3 left halo float4s (cols wc0-16..wc0-1),
    //       lanes 4-7 right halo float4s (cols wc0+512..wc0+527)
    int hcol = 0;
    const bool hlane = (l < 8);
    if (l < 4)      hcol = wc0 - 16 + 4 * l;
    else if (l < 8) hcol = wc0 + 512 + 4 * (l - 4);
    const bool hvalid = hlane && (hcol >= 0) && (hcol < WW);
    const int  hw_    = (l < 4) ? 4 * l : 528 + 4 * (l - 4);  // logical word
    const int  hidx   = swz4(hw_);                            // swizzled

    const int ow0 = swz4(16 + 8 * l);        // owned write base (quad a)
    const int ow1 = swz4(20 + 8 * l);        // owned write base (quad b)

    const float* __restrict__ img  = x   + (size_t)b * HH * WW;
    float* __restrict__       oimg = out + (size_t)b * HH * WW;

    float4 sa = make_float4(0.f, 0.f, 0.f, 0.f);   // vertical sums c0..c0+3
    float4 sb = make_float4(0.f, 0.f, 0.f, 0.f);   // c0+4..c0+7
    float4 qa = make_float4(0.f, 0.f, 0.f, 0.f);   // vertical sq-sums
    float4 qb = make_float4(0.f, 0.f, 0.f, 0.f);
    float4 hs  = make_float4(0.f, 0.f, 0.f, 0.f);  // halo sums
    float4 hs2 = make_float4(0.f, 0.f, 0.f, 0.f);

    // --- init vertical sliding sums for output row r0 ---
    {
        int lo = r0 - PADK; if (lo < 0) lo = 0;
        int hi = r0 + PADK; if (hi > HH - 1) hi = HH - 1;
        for (int r = lo; r <= hi; ++r) {
            const float* rowp = img + (size_t)r * WW;
            float4 va = ld4(rowp + c0);
            float4 vb = ld4(rowp + c0 + 4);
            sa.x += va.x;       sa.y += va.y;       sa.z += va.z;       sa.w += va.w;
            sb.x += vb.x;       sb.y += vb.y;       sb.z += vb.z;       sb.w += vb.w;
            qa.x += va.x*va.x;  qa.y += va.y*va.y;  qa.z += va.z*va.z;  qa.w += va.w*va.w;
            qb.x += vb.x*vb.x;  qb.y += vb.y*vb.y;  qb.z += vb.z*vb.z;  qb.w += vb.w*vb.w;
            if (hvalid) {
                float4 hv = ld4(rowp + hcol);
                hs.x  += hv.x;       hs.y  += hv.y;       hs.z  += hv.z;       hs.w  += hv.w;
                hs2.x += hv.x*hv.x;  hs2.y += hv.y*hv.y;  hs2.z += hv.z*hv.z;  hs2.w += hv.w*hv.w;
            }
        }
    }

    for (int i = 0; i < RB; ++i) {
        const int orow = r0 + i;
        if (i > 0) {
            const int radd = orow + PADK;
            const int rsub = orow - PADK - 1;
            if (radd < HH) {
                const float* rowp = img + (size_t)radd * WW;
                float4 va = ld4(rowp + c0);
                float4 vb = ld4(rowp + c0 + 4);
                sa.x += va.x;       sa.y += va.y;       sa.z += va.z;       sa.w += va.w;
                sb.x += vb.x;       sb.y += vb.y;       sb.z += vb.z;       sb.w += vb.w;
                qa.x += va.x*va.x;  qa.y += va.y*va.y;  qa.z += va.z*va.z;  qa.w += va.w*va.w;
                qb.x += vb.x*vb.x;  qb.y += vb.y*vb.y;  qb.z += vb.z*vb.z;  qb.w += vb.w*vb.w;
                if (hvalid) {
                    float4 hv = ld4(rowp + hcol);
                    hs.x  += hv.x;       hs.y  += hv.y;       hs.z  += hv.z;       hs.w  += hv.w;
                    hs2.x += hv.x*hv.x;  hs2.y += hv.y*hv.y;  hs2.z += hv.z*hv.z;  hs2.w += hv.w*hv.w;
                }
            }
            if (rsub >= 0) {
                const float* rowp = img + (size_t)rsub * WW;
                float4 va = ld4(rowp + c0);
                float4 vb = ld4(rowp + c0 + 4);
                sa.x -= va.x;       sa.y -= va.y;       sa.z -= va.z;       sa.w -= va.w;
                sb.x -= vb.x;       sb.y -= vb.y;       sb.z -= vb.z;       sb.w -= vb.w;
                qa.x -= va.x*va.x;  qa.y -= va.y*va.y;  qa.z -= va.z*va.z;  qa.w -= va.w*va.w;
                qb.x -= vb.x*vb.x;  qb.y -= vb.y*vb.y;  qb.z -= vb.z*vb.z;  qb.w -= vb.w*vb.w;
                if (hvalid) {
                    float4 hv = ld4(rowp + hcol);
                    hs.x  -= hv.x;       hs.y  -= hv.y;       hs.z  -= hv.z;       hs.w  -= hv.w;
                    hs2.x -= hv.x*hv.x;  hs2.y -= hv.y*hv.y;  hs2.z -= hv.z*hv.z;  hs2.w -= hv.w*hv.w;
                }
            }
        }

        // write this wave's vertical sums (owned + halo), swizzled
        *reinterpret_cast<float4*>(sxw + ow0) = sa;
        *reinterpret_cast<float4*>(sxw + ow1) = sb;
        *reinterpret_cast<float4*>(sqw + ow0) = qa;
        *reinterpret_cast<float4*>(sqw + ow1) = qb;
        if (hlane) {
            *reinterpret_cast<float4*>(sxw + hidx) = hs;    // zeros when !hvalid
            *reinterpret_cast<float4*>(sqw + hidx) = hs2;
        }
        // no barrier: DS ops are in-order within a wave

        // --- horizontal 31-window sums for the 8 owned cols ---
        float winx[8], winq[8];
        hwin31(sxw, bw, winx);
        hwin31(sqw, bw, winq);

        const float4 xc0 = ld4(img + (size_t)orow * WW + c0);
        const float4 xc1 = ld4(img + (size_t)orow * WW + c0 + 4);
        const float xcv[8] = {xc0.x, xc0.y, xc0.z, xc0.w,
                              xc1.x, xc1.y, xc1.z, xc1.w};
        float res[8];
        #pragma unroll
        for (int q = 0; q < 8; ++q) {
            float mean = winx[q] * INV_K2;
            float sq   = winq[q] * INV_K2;
            float sd   = sqrtf(fmaxf(sq - mean * mean, EPSV));
            float nrm  = (xcv[q] - mean) * __builtin_amdgcn_rcpf(sd + EPSV);
            float e    = __expf(-0.5f * nrm);
            res[q] = xcv[q] * 0.2f + 0.8f * __builtin_amdgcn_rcpf(1.0f + e);
        }
        float4 o0 = make_float4(res[0], res[1], res[2], res[3]);
        float4 o1 = make_float4(res[4], res[5], res[6], res[7]);
        *reinterpret_cast<float4*>(oimg + (size_t)orow * WW + c0)     = o0;
        *reinterpret_cast<float4*>(oimg + (size_t)orow * WW + c0 + 4) = o1;
    }
}

extern "C" void kernel_launch(void* const* d_in, const int* in_sizes, int n_in,
                              void* d_out, int out_size, void* d_ws, size_t ws_size,
                              hipStream_t stream) {
    const float* xin = (const float*)d_in[0];
    float* out = (float*)d_out;
    const int B = in_sizes[0] / (HH * WW);   // 32
    dim3 grid(B * 32);                       // 1024 blocks x 8 waves
    dim3 block(TPB);
    hipLaunchKernelGGL(lcn_kernel, grid, block, 0, stream, xin, out);
}

// Round 9
// 126.960 us; speedup vs baseline: 1.1854x; 1.0886x over previous
//
#include <hip/hip_runtime.h>
#include <math.h>

#define HH 1024
#define WW 1024
#define PADK 15
#define RB 8
#define TPB 512
#define EPSV 1e-5f
#define INV_K2 (1.0f / 961.0f)

__device__ __forceinline__ float4 ld4(const float* p) {
    return *reinterpret_cast<const float4*>(p);
}

// XOR bank swizzle on LDS word index: b2 ^= b5 (r8-verified: conflicts 47M->6.8M).
__device__ __forceinline__ int swz4(int w) {
    return w ^ (((w >> 5) & 1) << 2);
}

// Horizontal 31-window sums for the 8 consecutive cols owned by a lane
// (r7/r8-verified arithmetic).
__device__ __forceinline__ void hwin31(const float* __restrict__ sw, int bw,
                                       float wins[8]) {
    float4 R0 = ld4(sw + swz4(bw));        // wv[0..3]
    float4 R1 = ld4(sw + swz4(bw + 4));    // wv[4..7]
    float4 v2 = ld4(sw + swz4(bw + 8));
    float4 v3 = ld4(sw + swz4(bw + 12));
    float4 v4 = ld4(sw + swz4(bw + 16));
    float4 v5 = ld4(sw + swz4(bw + 20));
    float4 v6 = ld4(sw + swz4(bw + 24));
    float4 v7 = ld4(sw + swz4(bw + 28));   // ..wv[31]
    float4 R8 = ld4(sw + swz4(bw + 32));   // wv[32..35]
    float4 R9 = ld4(sw + swz4(bw + 36));   // wv[36..39]

    float a0 = R1.x, a1 = R1.y, a2 = R1.z, a3 = R1.w;
    a0 += v2.x; a1 += v2.y; a2 += v2.z; a3 += v2.w;
    a0 += v3.x; a1 += v3.y; a2 += v3.z; a3 += v3.w;
    a0 += v4.x; a1 += v4.y; a2 += v4.z; a3 += v4.w;
    a0 += v5.x; a1 += v5.y; a2 += v5.z; a3 += v5.w;
    a0 += v6.x; a1 += v6.y; a2 += v6.z; a3 += v6.w;
    a0 += v7.x; a1 += v7.y; a2 += v7.z; a3 += v7.w;
    float base = (a0 + a1) + (a2 + a3);               // wv[4..31]

    wins[0] = base + ((R0.y + R0.z) + R0.w);          // + wv[1..3]
    wins[1] = wins[0] + (R8.x - R0.y);
    wins[2] = wins[1] + (R8.y - R0.z);
    wins[3] = wins[2] + (R8.z - R0.w);
    wins[4] = wins[3] + (R8.w - R1.x);
    wins[5] = wins[4] + (R9.x - R1.y);
    wins[6] = wins[5] + (R9.y - R1.z);
    wins[7] = wins[6] + (R9.z - R1.w);
}

__global__ __launch_bounds__(TPB) void lcn_kernel(const float* __restrict__ x,
                                                  float* __restrict__ out) {
    // r8 structure: 8 waves/block = 2 col-halves x 4 row-bands of 8 rows
    // (32-row slab), 8 cols/lane, swizzled per-wave LDS, no __syncthreads.
    // NEW (single change): bijective XCD-chunked block swizzle. Hardware
    // round-robins dispatch bid across 8 XCDs; remap so XCD x owns images
    // 4x..4x+3 entirely. All 32 slabs of an image then run on ONE XCD ->
    // overlapping halo rows (adjacent slabs + intra-block bands) become
    // L2 hits instead of cross-XCD HBM re-reads.
    __shared__ __align__(16) float sxl[8][552];
    __shared__ __align__(16) float sql[8][552];

    const int bid  = blockIdx.x;
    const int xcd  = bid & 7;           // hw XCD (round-robin heuristic)
    const int k    = bid >> 3;          // 0..127
    const int b    = xcd * 4 + (k >> 5);   // image: 4 per XCD
    const int seg  = k & 31;            // 32-row slab within image
    const int t    = threadIdx.x;
    const int w    = t >> 6;            // wave 0..7
    const int l    = t & 63;            // lane
    const int half = w & 1;             // column half
    const int band = w >> 1;            // row band 0..3
    const int r0   = seg * 32 + band * RB;
    const int wc0  = half * 512;
    const int c0   = wc0 + l * 8;       // lane owns cols c0..c0+7
    const int bw   = 8 * l;             // window read base (logical word)

    float* __restrict__ sxw = sxl[w];
    float* __restrict__ sqw = sql[w];

    // halo: lanes 0-3 left halo float4s, lanes 4-7 right halo float4s
    int hcol = 0;
    const bool hlane = (l < 8);
    if (l < 4)      hcol = wc0 - 16 + 4 * l;
    else if (l < 8) hcol = wc0 + 512 + 4 * (l - 4);
    const bool hvalid = hlane && (hcol >= 0) && (hcol < WW);
    const int  hw_    = (l < 4) ? 4 * l : 528 + 4 * (l - 4);  // logical word
    const int  hidx   = swz4(hw_);                            // swizzled

    const int ow0 = swz4(16 + 8 * l);        // owned write base (quad a)
    const int ow1 = swz4(20 + 8 * l);        // owned write base (quad b)

    const float* __restrict__ img  = x   + (size_t)b * HH * WW;
    float* __restrict__       oimg = out + (size_t)b * HH * WW;

    float4 sa = make_float4(0.f, 0.f, 0.f, 0.f);   // vertical sums c0..c0+3
    float4 sb = make_float4(0.f, 0.f, 0.f, 0.f);   // c0+4..c0+7
    float4 qa = make_float4(0.f, 0.f, 0.f, 0.f);   // vertical sq-sums
    float4 qb = make_float4(0.f, 0.f, 0.f, 0.f);
    float4 hs  = make_float4(0.f, 0.f, 0.f, 0.f);  // halo sums
    float4 hs2 = make_float4(0.f, 0.f, 0.f, 0.f);

    // --- init vertical sliding sums for output row r0 ---
    {
        int lo = r0 - PADK; if (lo < 0) lo = 0;
        int hi = r0 + PADK; if (hi > HH - 1) hi = HH - 1;
        for (int r = lo; r <= hi; ++r) {
            const float* rowp = img + (size_t)r * WW;
            float4 va = ld4(rowp + c0);
            float4 vb = ld4(rowp + c0 + 4);
            sa.x += va.x;       sa.y += va.y;       sa.z += va.z;       sa.w += va.w;
            sb.x += vb.x;       sb.y += vb.y;       sb.z += vb.z;       sb.w += vb.w;
            qa.x += va.x*va.x;  qa.y += va.y*va.y;  qa.z += va.z*va.z;  qa.w += va.w*va.w;
            qb.x += vb.x*vb.x;  qb.y += vb.y*vb.y;  qb.z += vb.z*vb.z;  qb.w += vb.w*vb.w;
            if (hvalid) {
                float4 hv = ld4(rowp + hcol);
                hs.x  += hv.x;       hs.y  += hv.y;       hs.z  += hv.z;       hs.w  += hv.w;
                hs2.x += hv.x*hv.x;  hs2.y += hv.y*hv.y;  hs2.z += hv.z*hv.z;  hs2.w += hv.w*hv.w;
            }
        }
    }

    for (int i = 0; i < RB; ++i) {
        const int orow = r0 + i;
        if (i > 0) {
            const int radd = orow + PADK;
            const int rsub = orow - PADK - 1;
            if (radd < HH) {
                const float* rowp = img + (size_t)radd * WW;
                float4 va = ld4(rowp + c0);
                float4 vb = ld4(rowp + c0 + 4);
                sa.x += va.x;       sa.y += va.y;       sa.z += va.z;       sa.w += va.w;
                sb.x += vb.x;       sb.y += vb.y;       sb.z += vb.z;       sb.w += vb.w;
                qa.x += va.x*va.x;  qa.y += va.y*va.y;  qa.z += va.z*va.z;  qa.w += va.w*va.w;
                qb.x += vb.x*vb.x;  qb.y += vb.y*vb.y;  qb.z += vb.z*vb.z;  qb.w += vb.w*vb.w;
                if (hvalid) {
                    float4 hv = ld4(rowp + hcol);
                    hs.x  += hv.x;       hs.y  += hv.y;       hs.z  += hv.z;       hs.w  += hv.w;
                    hs2.x += hv.x*hv.x;  hs2.y += hv.y*hv.y;  hs2.z += hv.z*hv.z;  hs2.w += hv.w*hv.w;
                }
            }
            if (rsub >= 0) {
                const float* rowp = img + (size_t)rsub * WW;
                float4 va = ld4(rowp + c0);
                float4 vb = ld4(rowp + c0 + 4);
                sa.x -= va.x;       sa.y -= va.y;       sa.z -= va.z;       sa.w -= va.w;
                sb.x -= vb.x;       sb.y -= vb.y;       sb.z -= vb.z;       sb.w -= vb.w;
                qa.x -= va.x*va.x;  qa.y -= va.y*va.y;  qa.z -= va.z*va.z;  qa.w -= va.w*va.w;
                qb.x -= vb.x*vb.x;  qb.y -= vb.y*vb.y;  qb.z -= vb.z*vb.z;  qb.w -= vb.w*vb.w;
                if (hvalid) {
                    float4 hv = ld4(rowp + hcol);
                    hs.x  -= hv.x;       hs.y  -= hv.y;       hs.z  -= hv.z;       hs.w  -= hv.w;
                    hs2.x -= hv.x*hv.x;  hs2.y -= hv.y*hv.y;  hs2.z -= hv.z*hv.z;  hs2.w -= hv.w*hv.w;
                }
            }
        }

        // write this wave's vertical sums (owned + halo), swizzled
        *reinterpret_cast<float4*>(sxw + ow0) = sa;
        *reinterpret_cast<float4*>(sxw + ow1) = sb;
        *reinterpret_cast<float4*>(sqw + ow0) = qa;
        *reinterpret_cast<float4*>(sqw + ow1) = qb;
        if (hlane) {
            *reinterpret_cast<float4*>(sxw + hidx) = hs;    // zeros when !hvalid
            *reinterpret_cast<float4*>(sqw + hidx) = hs2;
        }
        // no barrier: DS ops are in-order within a wave

        // --- horizontal 31-window sums for the 8 owned cols ---
        float winx[8], winq[8];
        hwin31(sxw, bw, winx);
        hwin31(sqw, bw, winq);

        const float4 xc0 = ld4(img + (size_t)orow * WW + c0);
        const float4 xc1 = ld4(img + (size_t)orow * WW + c0 + 4);
        const float xcv[8] = {xc0.x, xc0.y, xc0.z, xc0.w,
                              xc1.x, xc1.y, xc1.z, xc1.w};
        float res[8];
        #pragma unroll
        for (int q = 0; q < 8; ++q) {
            float mean = winx[q] * INV_K2;
            float sq   = winq[q] * INV_K2;
            float sd   = sqrtf(fmaxf(sq - mean * mean, EPSV));
            float nrm  = (xcv[q] - mean) * __builtin_amdgcn_rcpf(sd + EPSV);
            float e    = __expf(-0.5f * nrm);
            res[q] = xcv[q] * 0.2f + 0.8f * __builtin_amdgcn_rcpf(1.0f + e);
        }
        float4 o0 = make_float4(res[0], res[1], res[2], res[3]);
        float4 o1 = make_float4(res[4], res[5], res[6], res[7]);
        *reinterpret_cast<float4*>(oimg + (size_t)orow * WW + c0)     = o0;
        *reinterpret_cast<float4*>(oimg + (size_t)orow * WW + c0 + 4) = o1;
    }
}

extern "C" void kernel_launch(void* const* d_in, const int* in_sizes, int n_in,
                              void* d_out, int out_size, void* d_ws, size_t ws_size,
                              hipStream_t stream) {
    const float* xin = (const float*)d_in[0];
    float* out = (float*)d_out;
    const int B = in_sizes[0] / (HH * WW);   // 32
    dim3 grid(B * 32);                       // 1024 blocks x 8 waves
    dim3 block(TPB);
    hipLaunchKernelGGL(lcn_kernel, grid, block, 0, stream, xin, out);
}

// Round 10
// 99.684 us; speedup vs baseline: 1.5097x; 1.2736x over previous
//
#include <hip/hip_runtime.h>
#include <math.h>

#define HH 1024
#define WW 1024
#define PADK 15
#define RB 16
#define TPB 512
#define EPSV 1e-5f
#define INV_K2 (1.0f / 961.0f)

__device__ __forceinline__ float4 ld4(const float* p) {
    return *reinterpret_cast<const float4*>(p);
}

// XOR bank swizzle on LDS word index: b2 ^= b5 (r8-verified: conflicts 47M->6.8M).
__device__ __forceinline__ int swz4(int w) {
    return w ^ (((w >> 5) & 1) << 2);
}

// Horizontal 31-window sums for the 8 consecutive cols owned by a lane
// (r7/r8/r9-verified arithmetic).
__device__ __forceinline__ void hwin31(const float* __restrict__ sw, int bw,
                                       float wins[8]) {
    float4 R0 = ld4(sw + swz4(bw));        // wv[0..3]
    float4 R1 = ld4(sw + swz4(bw + 4));    // wv[4..7]
    float4 v2 = ld4(sw + swz4(bw + 8));
    float4 v3 = ld4(sw + swz4(bw + 12));
    float4 v4 = ld4(sw + swz4(bw + 16));
    float4 v5 = ld4(sw + swz4(bw + 20));
    float4 v6 = ld4(sw + swz4(bw + 24));
    float4 v7 = ld4(sw + swz4(bw + 28));   // ..wv[31]
    float4 R8 = ld4(sw + swz4(bw + 32));   // wv[32..35]
    float4 R9 = ld4(sw + swz4(bw + 36));   // wv[36..39]

    float a0 = R1.x, a1 = R1.y, a2 = R1.z, a3 = R1.w;
    a0 += v2.x; a1 += v2.y; a2 += v2.z; a3 += v2.w;
    a0 += v3.x; a1 += v3.y; a2 += v3.z; a3 += v3.w;
    a0 += v4.x; a1 += v4.y; a2 += v4.z; a3 += v4.w;
    a0 += v5.x; a1 += v5.y; a2 += v5.z; a3 += v5.w;
    a0 += v6.x; a1 += v6.y; a2 += v6.z; a3 += v6.w;
    a0 += v7.x; a1 += v7.y; a2 += v7.z; a3 += v7.w;
    float base = (a0 + a1) + (a2 + a3);               // wv[4..31]

    wins[0] = base + ((R0.y + R0.z) + R0.w);          // + wv[1..3]
    wins[1] = wins[0] + (R8.x - R0.y);
    wins[2] = wins[1] + (R8.y - R0.z);
    wins[3] = wins[2] + (R8.z - R0.w);
    wins[4] = wins[3] + (R8.w - R1.x);
    wins[5] = wins[4] + (R9.x - R1.y);
    wins[6] = wins[5] + (R9.y - R1.z);
    wins[7] = wins[6] + (R9.z - R1.w);
}

__global__ __launch_bounds__(TPB) void lcn_kernel(const float* __restrict__ x,
                                                  float* __restrict__ out) {
    // 8 waves/block = 2 col-halves x 4 row-bands of 16 rows -> 64-row slab
    // (reads 94 rows for 64 output: block amp 1.47x, bands share halo rows
    // via L2). Wave owns a 512-col stripe, 8 cols/lane, swizzled per-wave
    // LDS, no __syncthreads. XCD-chunked block swizzle: XCD x owns images
    // 4x..4x+3; all 16 slabs of an image run on one XCD.
    __shared__ __align__(16) float sxl[8][552];
    __shared__ __align__(16) float sql[8][552];

    const int bid  = blockIdx.x;
    const int xcd  = bid & 7;           // hw XCD (round-robin heuristic)
    const int k    = bid >> 3;          // 0..63
    const int b    = xcd * 4 + (k >> 4);   // image: 4 per XCD
    const int seg  = k & 15;            // 64-row slab within image
    const int t    = threadIdx.x;
    const int w    = t >> 6;            // wave 0..7
    const int l    = t & 63;            // lane
    const int half = w & 1;             // column half
    const int band = w >> 1;            // row band 0..3
    const int r0   = seg * 64 + band * RB;
    const int wc0  = half * 512;
    const int c0   = wc0 + l * 8;       // lane owns cols c0..c0+7
    const int bw   = 8 * l;             // window read base (logical word)

    float* __restrict__ sxw = sxl[w];
    float* __restrict__ sqw = sql[w];

    // halo: lanes 0-3 left halo float4s, lanes 4-7 right halo float4s
    int hcol = 0;
    const bool hlane = (l < 8);
    if (l < 4)      hcol = wc0 - 16 + 4 * l;
    else if (l < 8) hcol = wc0 + 512 + 4 * (l - 4);
    const bool hvalid = hlane && (hcol >= 0) && (hcol < WW);
    const int  hw_    = (l < 4) ? 4 * l : 528 + 4 * (l - 4);  // logical word
    const int  hidx   = swz4(hw_);                            // swizzled

    const int ow0 = swz4(16 + 8 * l);        // owned write base (quad a)
    const int ow1 = swz4(20 + 8 * l);        // owned write base (quad b)

    const float* __restrict__ img  = x   + (size_t)b * HH * WW;
    float* __restrict__       oimg = out + (size_t)b * HH * WW;

    float4 sa = make_float4(0.f, 0.f, 0.f, 0.f);   // vertical sums c0..c0+3
    float4 sb = make_float4(0.f, 0.f, 0.f, 0.f);   // c0+4..c0+7
    float4 qa = make_float4(0.f, 0.f, 0.f, 0.f);   // vertical sq-sums
    float4 qb = make_float4(0.f, 0.f, 0.f, 0.f);
    float4 hs  = make_float4(0.f, 0.f, 0.f, 0.f);  // halo sums
    float4 hs2 = make_float4(0.f, 0.f, 0.f, 0.f);

    // --- init vertical sliding sums for output row r0 ---
    {
        int lo = r0 - PADK; if (lo < 0) lo = 0;
        int hi = r0 + PADK; if (hi > HH - 1) hi = HH - 1;
        for (int r = lo; r <= hi; ++r) {
            const float* rowp = img + (size_t)r * WW;
            float4 va = ld4(rowp + c0);
            float4 vb = ld4(rowp + c0 + 4);
            sa.x += va.x;       sa.y += va.y;       sa.z += va.z;       sa.w += va.w;
            sb.x += vb.x;       sb.y += vb.y;       sb.z += vb.z;       sb.w += vb.w;
            qa.x += va.x*va.x;  qa.y += va.y*va.y;  qa.z += va.z*va.z;  qa.w += va.w*va.w;
            qb.x += vb.x*vb.x;  qb.y += vb.y*vb.y;  qb.z += vb.z*vb.z;  qb.w += vb.w*vb.w;
            if (hvalid) {
                float4 hv = ld4(rowp + hcol);
                hs.x  += hv.x;       hs.y  += hv.y;       hs.z  += hv.z;       hs.w  += hv.w;
                hs2.x += hv.x*hv.x;  hs2.y += hv.y*hv.y;  hs2.z += hv.z*hv.z;  hs2.w += hv.w*hv.w;
            }
        }
    }

    for (int i = 0; i < RB; ++i) {
        const int orow = r0 + i;
        if (i > 0) {
            const int radd = orow + PADK;
            const int rsub = orow - PADK - 1;
            if (radd < HH) {
                const float* rowp = img + (size_t)radd * WW;
                float4 va = ld4(rowp + c0);
                float4 vb = ld4(rowp + c0 + 4);
                sa.x += va.x;       sa.y += va.y;       sa.z += va.z;       sa.w += va.w;
                sb.x += vb.x;       sb.y += vb.y;       sb.z += vb.z;       sb.w += vb.w;
                qa.x += va.x*va.x;  qa.y += va.y*va.y;  qa.z += va.z*va.z;  qa.w += va.w*va.w;
                qb.x += vb.x*vb.x;  qb.y += vb.y*vb.y;  qb.z += vb.z*vb.z;  qb.w += vb.w*vb.w;
                if (hvalid) {
                    float4 hv = ld4(rowp + hcol);
                    hs.x  += hv.x;       hs.y  += hv.y;       hs.z  += hv.z;       hs.w  += hv.w;
                    hs2.x += hv.x*hv.x;  hs2.y += hv.y*hv.y;  hs2.z += hv.z*hv.z;  hs2.w += hv.w*hv.w;
                }
            }
            if (rsub >= 0) {
                const float* rowp = img + (size_t)rsub * WW;
                float4 va = ld4(rowp + c0);
                float4 vb = ld4(rowp + c0 + 4);
                sa.x -= va.x;       sa.y -= va.y;       sa.z -= va.z;       sa.w -= va.w;
                sb.x -= vb.x;       sb.y -= vb.y;       sb.z -= vb.z;       sb.w -= vb.w;
                qa.x -= va.x*va.x;  qa.y -= va.y*va.y;  qa.z -= va.z*va.z;  qa.w -= va.w*va.w;
                qb.x -= vb.x*vb.x;  qb.y -= vb.y*vb.y;  qb.z -= vb.z*vb.z;  qb.w -= vb.w*vb.w;
                if (hvalid) {
                    float4 hv = ld4(rowp + hcol);
                    hs.x  -= hv.x;       hs.y  -= hv.y;       hs.z  -= hv.z;       hs.w  -= hv.w;
                    hs2.x -= hv.x*hv.x;  hs2.y -= hv.y*hv.y;  hs2.z -= hv.z*hv.z;  hs2.w -= hv.w*hv.w;
                }
            }
        }

        // write this wave's vertical sums (owned + halo), swizzled
        *reinterpret_cast<float4*>(sxw + ow0) = sa;
        *reinterpret_cast<float4*>(sxw + ow1) = sb;
        *reinterpret_cast<float4*>(sqw + ow0) = qa;
        *reinterpret_cast<float4*>(sqw + ow1) = qb;
        if (hlane) {
            *reinterpret_cast<float4*>(sxw + hidx) = hs;    // zeros when !hvalid
            *reinterpret_cast<float4*>(sqw + hidx) = hs2;
        }
        // no barrier: DS ops are in-order within a wave

        // --- horizontal 31-window sums for the 8 owned cols ---
        float winx[8], winq[8];
        hwin31(sxw, bw, winx);
        hwin31(sqw, bw, winq);

        const float4 xc0 = ld4(img + (size_t)orow * WW + c0);
        const float4 xc1 = ld4(img + (size_t)orow * WW + c0 + 4);
        const float xcv[8] = {xc0.x, xc0.y, xc0.z, xc0.w,
                              xc1.x, xc1.y, xc1.z, xc1.w};
        float res[8];
        #pragma unroll
        for (int q = 0; q < 8; ++q) {
            float mean = winx[q] * INV_K2;
            float sq   = winq[q] * INV_K2;
            float sd   = sqrtf(fmaxf(sq - mean * mean, EPSV));
            float nrm  = (xcv[q] - mean) * __builtin_amdgcn_rcpf(sd + EPSV);
            float e    = __expf(-0.5f * nrm);
            res[q] = xcv[q] * 0.2f + 0.8f * __builtin_amdgcn_rcpf(1.0f + e);
        }
        float4 o0 = make_float4(res[0], res[1], res[2], res[3]);
        float4 o1 = make_float4(res[4], res[5], res[6], res[7]);
        *reinterpret_cast<float4*>(oimg + (size_t)orow * WW + c0)     = o0;
        *reinterpret_cast<float4*>(oimg + (size_t)orow * WW + c0 + 4) = o1;
    }
}

extern "C" void kernel_launch(void* const* d_in, const int* in_sizes, int n_in,
                              void* d_out, int out_size, void* d_ws, size_t ws_size,
                              hipStream_t stream) {
    const float* xin = (const float*)d_in[0];
    float* out = (float*)d_out;
    const int B = in_sizes[0] / (HH * WW);   // 32
    dim3 grid(B * 16);                       // 512 blocks x 8 waves
    dim3 block(TPB);
    hipLaunchKernelGGL(lcn_kernel, grid, block, 0, stream, xin, out);
}